// Round 1
// baseline (4628.120 us; speedup 1.0000x reference)
//
#include <hip/hip_runtime.h>
#include <hip/hip_bf16.h>

// Problem constants
#define BB 64
#define TT 2048
#define II 128
#define HH 256
#define OO 128

// ---------------------------------------------------------------------------
// Tiled fp32 GEMM: C[M,N] = A[M,K] * B[N,K]^T + bias[N]
// BM=64, BN=64, BK=32, 256 threads, 4x4 micro-tile per thread.
// ---------------------------------------------------------------------------
#define BM 64
#define BN 64
#define BKT 32

__global__ __launch_bounds__(256) void gemm_f32_bt(
    const float* __restrict__ A, const float* __restrict__ B,
    const float* __restrict__ bias, float* __restrict__ C,
    int M, int N, int K)
{
    __shared__ __align__(16) float As[BKT][BM + 4];
    __shared__ __align__(16) float Bs[BKT][BN + 4];

    const int t  = threadIdx.x;
    const int m0 = blockIdx.x * BM;
    const int n0 = blockIdx.y * BN;
    const int r  = t >> 3;         // 0..31
    const int kq = (t & 7) * 4;    // 0,4,...,28
    const int tx = t & 15;
    const int ty = t >> 4;

    float acc[4][4] = {};

    for (int k0 = 0; k0 < K; k0 += BKT) {
        float4 a0 = *(const float4*)&A[(size_t)(m0 + r)      * K + k0 + kq];
        float4 a1 = *(const float4*)&A[(size_t)(m0 + r + 32) * K + k0 + kq];
        float4 b0 = *(const float4*)&B[(size_t)(n0 + r)      * K + k0 + kq];
        float4 b1 = *(const float4*)&B[(size_t)(n0 + r + 32) * K + k0 + kq];

        __syncthreads();   // protect LDS from previous iteration's readers
        As[kq + 0][r] = a0.x; As[kq + 1][r] = a0.y; As[kq + 2][r] = a0.z; As[kq + 3][r] = a0.w;
        As[kq + 0][r + 32] = a1.x; As[kq + 1][r + 32] = a1.y; As[kq + 2][r + 32] = a1.z; As[kq + 3][r + 32] = a1.w;
        Bs[kq + 0][r] = b0.x; Bs[kq + 1][r] = b0.y; Bs[kq + 2][r] = b0.z; Bs[kq + 3][r] = b0.w;
        Bs[kq + 0][r + 32] = b1.x; Bs[kq + 1][r + 32] = b1.y; Bs[kq + 2][r + 32] = b1.z; Bs[kq + 3][r + 32] = b1.w;
        __syncthreads();

#pragma unroll
        for (int k = 0; k < BKT; ++k) {
            float4 avv = *(const float4*)&As[k][ty * 4];
            float4 bvv = *(const float4*)&Bs[k][tx * 4];
            const float* av = &avv.x;
            const float* bv = &bvv.x;
#pragma unroll
            for (int i = 0; i < 4; ++i)
#pragma unroll
                for (int j = 0; j < 4; ++j)
                    acc[i][j] = fmaf(av[i], bv[j], acc[i][j]);
        }
    }

#pragma unroll
    for (int i = 0; i < 4; ++i) {
        float4 o;
        o.x = acc[i][0] + bias[n0 + tx * 4 + 0];
        o.y = acc[i][1] + bias[n0 + tx * 4 + 1];
        o.z = acc[i][2] + bias[n0 + tx * 4 + 2];
        o.w = acc[i][3] + bias[n0 + tx * 4 + 3];
        *(float4*)&C[(size_t)(m0 + ty * 4 + i) * N + n0 + tx * 4] = o;
    }
}

// Same GEMM but A is bf16 (hs), output fp32.
typedef unsigned short ushortv4 __attribute__((ext_vector_type(4)));

__device__ __forceinline__ float bf16bits_to_f32(unsigned short u) {
    return __uint_as_float((unsigned)u << 16);
}

__global__ __launch_bounds__(256) void gemm_bf16a_bt(
    const unsigned short* __restrict__ A, const float* __restrict__ B,
    const float* __restrict__ bias, float* __restrict__ C,
    int M, int N, int K)
{
    __shared__ __align__(16) float As[BKT][BM + 4];
    __shared__ __align__(16) float Bs[BKT][BN + 4];

    const int t  = threadIdx.x;
    const int m0 = blockIdx.x * BM;
    const int n0 = blockIdx.y * BN;
    const int r  = t >> 3;
    const int kq = (t & 7) * 4;
    const int tx = t & 15;
    const int ty = t >> 4;

    float acc[4][4] = {};

    for (int k0 = 0; k0 < K; k0 += BKT) {
        ushortv4 a0 = *(const ushortv4*)&A[(size_t)(m0 + r)      * K + k0 + kq];
        ushortv4 a1 = *(const ushortv4*)&A[(size_t)(m0 + r + 32) * K + k0 + kq];
        float4  b0 = *(const float4*)&B[(size_t)(n0 + r)      * K + k0 + kq];
        float4  b1 = *(const float4*)&B[(size_t)(n0 + r + 32) * K + k0 + kq];

        __syncthreads();
        As[kq + 0][r] = bf16bits_to_f32(a0[0]); As[kq + 1][r] = bf16bits_to_f32(a0[1]);
        As[kq + 2][r] = bf16bits_to_f32(a0[2]); As[kq + 3][r] = bf16bits_to_f32(a0[3]);
        As[kq + 0][r + 32] = bf16bits_to_f32(a1[0]); As[kq + 1][r + 32] = bf16bits_to_f32(a1[1]);
        As[kq + 2][r + 32] = bf16bits_to_f32(a1[2]); As[kq + 3][r + 32] = bf16bits_to_f32(a1[3]);
        Bs[kq + 0][r] = b0.x; Bs[kq + 1][r] = b0.y; Bs[kq + 2][r] = b0.z; Bs[kq + 3][r] = b0.w;
        Bs[kq + 0][r + 32] = b1.x; Bs[kq + 1][r + 32] = b1.y; Bs[kq + 2][r + 32] = b1.z; Bs[kq + 3][r + 32] = b1.w;
        __syncthreads();

#pragma unroll
        for (int k = 0; k < BKT; ++k) {
            float4 avv = *(const float4*)&As[k][ty * 4];
            float4 bvv = *(const float4*)&Bs[k][tx * 4];
            const float* av = &avv.x;
            const float* bv = &bvv.x;
#pragma unroll
            for (int i = 0; i < 4; ++i)
#pragma unroll
                for (int j = 0; j < 4; ++j)
                    acc[i][j] = fmaf(av[i], bv[j], acc[i][j]);
        }
    }

#pragma unroll
    for (int i = 0; i < 4; ++i) {
        float4 o;
        o.x = acc[i][0] + bias[n0 + tx * 4 + 0];
        o.y = acc[i][1] + bias[n0 + tx * 4 + 1];
        o.z = acc[i][2] + bias[n0 + tx * 4 + 2];
        o.w = acc[i][3] + bias[n0 + tx * 4 + 3];
        *(float4*)&C[(size_t)(m0 + ty * 4 + i) * N + n0 + tx * 4] = o;
    }
}

// ---------------------------------------------------------------------------
// Recurrence: 64 blocks (one per batch element), 256 threads (one per hidden
// unit). Wh row j lives in registers (256 fp32 VGPRs; launch_bounds(256,1)
// gives the 512-VGPR budget at 1 wave/SIMD). h lives in LDS; each step every
// thread does a 256-MAC dot product against broadcast ds_read_b128 of h.
// Fully fp32 on the recurrent path; hs stored as bf16 for the output GEMM.
// ---------------------------------------------------------------------------
__global__ __launch_bounds__(256, 1) void rnn_recurrence(
    const float* __restrict__ xproj, const float* __restrict__ Wh,
    const float* __restrict__ bh, __hip_bfloat16* __restrict__ hs)
{
    __shared__ __align__(16) float hsm[HH];

    const int b = blockIdx.x;    // batch element
    const int j = threadIdx.x;   // hidden unit

    // Load my Wh row into registers (one-time; cached, amortized over T steps)
    float whr[HH];
    const float* wrow = Wh + (size_t)j * HH;
#pragma unroll
    for (int q = 0; q < HH / 4; ++q) {
        float4 v = *(const float4*)&wrow[4 * q];
        whr[4 * q + 0] = v.x; whr[4 * q + 1] = v.y;
        whr[4 * q + 2] = v.z; whr[4 * q + 3] = v.w;
    }
    const float bhv = bh[j];

    hsm[j] = 0.0f;
    __syncthreads();

    const float* xp = xproj + (size_t)b * TT * HH + j;
    __hip_bfloat16* hout = hs + (size_t)b * TT * HH + j;

    float xp_cur = xp[0];
    for (int t = 0; t < TT; ++t) {
        // prefetch next timestep's xproj element (hidden under the dot product)
        float xp_next = (t + 1 < TT) ? xp[(size_t)(t + 1) * HH] : 0.0f;

        float a0 = 0.f, a1 = 0.f, a2 = 0.f, a3 = 0.f;
        const float4* h4 = (const float4*)hsm;
#pragma unroll
        for (int q = 0; q < HH / 4; ++q) {
            float4 hv = h4[q];   // wave-uniform address -> LDS broadcast
            a0 = fmaf(whr[4 * q + 0], hv.x, a0);
            a1 = fmaf(whr[4 * q + 1], hv.y, a1);
            a2 = fmaf(whr[4 * q + 2], hv.z, a2);
            a3 = fmaf(whr[4 * q + 3], hv.w, a3);
        }
        float pre = xp_cur + bhv + ((a0 + a1) + (a2 + a3));
        float h = tanhf(pre);

        __syncthreads();          // everyone done reading hsm for step t
        hsm[j] = h;
        hout[(size_t)t * HH] = __float2bfloat16(h);
        __syncthreads();          // h for step t+1 visible

        xp_cur = xp_next;
    }
}

// ---------------------------------------------------------------------------
extern "C" void kernel_launch(void* const* d_in, const int* in_sizes, int n_in,
                              void* d_out, int out_size, void* d_ws, size_t ws_size,
                              hipStream_t stream)
{
    const float* x  = (const float*)d_in[0];   // [B,T,I]
    const float* Wi = (const float*)d_in[1];   // [H,I]
    const float* bi = (const float*)d_in[2];   // [H]
    const float* Wh = (const float*)d_in[3];   // [H,H]
    const float* bh = (const float*)d_in[4];   // [H]
    const float* Wo = (const float*)d_in[5];   // [O,H]
    const float* bo = (const float*)d_in[6];   // [O]
    float* out = (float*)d_out;                // [B,T,O] fp32

    const int M = BB * TT;                     // 131072 flattened rows

    // workspace layout: xproj fp32 [M,H] (134MB) | hs bf16 [M,H] (67MB)
    float* xproj = (float*)d_ws;
    __hip_bfloat16* hs = (__hip_bfloat16*)((char*)d_ws + (size_t)M * HH * sizeof(float));

    // Phase 1: xproj = x * Wi^T + bi
    gemm_f32_bt<<<dim3(M / BM, HH / BN), 256, 0, stream>>>(x, Wi, bi, xproj, M, HH, II);

    // Phase 2: sequential recurrence over T, parallel over batch
    rnn_recurrence<<<dim3(BB), 256, 0, stream>>>(xproj, Wh, bh, hs);

    // Phase 3: out = hs * Wo^T + bo
    gemm_bf16a_bt<<<dim3(M / BM, OO / BN), 256, 0, stream>>>(
        (const unsigned short*)hs, Wo, bo, out, M, OO, HH);
}

// Round 2
// 2250.352 us; speedup vs baseline: 2.0566x; 2.0566x over previous
//
#include <hip/hip_runtime.h>
#include <hip/hip_bf16.h>

// Problem constants
#define BB 64
#define TT 2048
#define II 128
#define HH 256
#define OO 128

typedef float f32x2 __attribute__((ext_vector_type(2)));

// ---------------------------------------------------------------------------
// Tiled fp32 GEMM: C[M,N] = A[M,K] * B[N,K]^T + bias[N]   (unchanged from R1)
// ---------------------------------------------------------------------------
#define BM 64
#define BN 64
#define BKT 32

__global__ __launch_bounds__(256) void gemm_f32_bt(
    const float* __restrict__ A, const float* __restrict__ B,
    const float* __restrict__ bias, float* __restrict__ C,
    int M, int N, int K)
{
    __shared__ __align__(16) float As[BKT][BM + 4];
    __shared__ __align__(16) float Bs[BKT][BN + 4];

    const int t  = threadIdx.x;
    const int m0 = blockIdx.x * BM;
    const int n0 = blockIdx.y * BN;
    const int r  = t >> 3;         // 0..31
    const int kq = (t & 7) * 4;    // 0,4,...,28
    const int tx = t & 15;
    const int ty = t >> 4;

    float acc[4][4] = {};

    for (int k0 = 0; k0 < K; k0 += BKT) {
        float4 a0 = *(const float4*)&A[(size_t)(m0 + r)      * K + k0 + kq];
        float4 a1 = *(const float4*)&A[(size_t)(m0 + r + 32) * K + k0 + kq];
        float4 b0 = *(const float4*)&B[(size_t)(n0 + r)      * K + k0 + kq];
        float4 b1 = *(const float4*)&B[(size_t)(n0 + r + 32) * K + k0 + kq];

        __syncthreads();
        As[kq + 0][r] = a0.x; As[kq + 1][r] = a0.y; As[kq + 2][r] = a0.z; As[kq + 3][r] = a0.w;
        As[kq + 0][r + 32] = a1.x; As[kq + 1][r + 32] = a1.y; As[kq + 2][r + 32] = a1.z; As[kq + 3][r + 32] = a1.w;
        Bs[kq + 0][r] = b0.x; Bs[kq + 1][r] = b0.y; Bs[kq + 2][r] = b0.z; Bs[kq + 3][r] = b0.w;
        Bs[kq + 0][r + 32] = b1.x; Bs[kq + 1][r + 32] = b1.y; Bs[kq + 2][r + 32] = b1.z; Bs[kq + 3][r + 32] = b1.w;
        __syncthreads();

#pragma unroll
        for (int k = 0; k < BKT; ++k) {
            float4 avv = *(const float4*)&As[k][ty * 4];
            float4 bvv = *(const float4*)&Bs[k][tx * 4];
            const float* av = &avv.x;
            const float* bv = &bvv.x;
#pragma unroll
            for (int i = 0; i < 4; ++i)
#pragma unroll
                for (int j = 0; j < 4; ++j)
                    acc[i][j] = fmaf(av[i], bv[j], acc[i][j]);
        }
    }

#pragma unroll
    for (int i = 0; i < 4; ++i) {
        float4 o;
        o.x = acc[i][0] + bias[n0 + tx * 4 + 0];
        o.y = acc[i][1] + bias[n0 + tx * 4 + 1];
        o.z = acc[i][2] + bias[n0 + tx * 4 + 2];
        o.w = acc[i][3] + bias[n0 + tx * 4 + 3];
        *(float4*)&C[(size_t)(m0 + ty * 4 + i) * N + n0 + tx * 4] = o;
    }
}

// Same GEMM but A is bf16 (hs), output fp32.  (unchanged from R1)
typedef unsigned short ushortv4 __attribute__((ext_vector_type(4)));

__device__ __forceinline__ float bf16bits_to_f32(unsigned short u) {
    return __uint_as_float((unsigned)u << 16);
}

__global__ __launch_bounds__(256) void gemm_bf16a_bt(
    const unsigned short* __restrict__ A, const float* __restrict__ B,
    const float* __restrict__ bias, float* __restrict__ C,
    int M, int N, int K)
{
    __shared__ __align__(16) float As[BKT][BM + 4];
    __shared__ __align__(16) float Bs[BKT][BN + 4];

    const int t  = threadIdx.x;
    const int m0 = blockIdx.x * BM;
    const int n0 = blockIdx.y * BN;
    const int r  = t >> 3;
    const int kq = (t & 7) * 4;
    const int tx = t & 15;
    const int ty = t >> 4;

    float acc[4][4] = {};

    for (int k0 = 0; k0 < K; k0 += BKT) {
        ushortv4 a0 = *(const ushortv4*)&A[(size_t)(m0 + r)      * K + k0 + kq];
        ushortv4 a1 = *(const ushortv4*)&A[(size_t)(m0 + r + 32) * K + k0 + kq];
        float4  b0 = *(const float4*)&B[(size_t)(n0 + r)      * K + k0 + kq];
        float4  b1 = *(const float4*)&B[(size_t)(n0 + r + 32) * K + k0 + kq];

        __syncthreads();
        As[kq + 0][r] = bf16bits_to_f32(a0[0]); As[kq + 1][r] = bf16bits_to_f32(a0[1]);
        As[kq + 2][r] = bf16bits_to_f32(a0[2]); As[kq + 3][r] = bf16bits_to_f32(a0[3]);
        As[kq + 0][r + 32] = bf16bits_to_f32(a1[0]); As[kq + 1][r + 32] = bf16bits_to_f32(a1[1]);
        As[kq + 2][r + 32] = bf16bits_to_f32(a1[2]); As[kq + 3][r + 32] = bf16bits_to_f32(a1[3]);
        Bs[kq + 0][r] = b0.x; Bs[kq + 1][r] = b0.y; Bs[kq + 2][r] = b0.z; Bs[kq + 3][r] = b0.w;
        Bs[kq + 0][r + 32] = b1.x; Bs[kq + 1][r + 32] = b1.y; Bs[kq + 2][r + 32] = b1.z; Bs[kq + 3][r + 32] = b1.w;
        __syncthreads();

#pragma unroll
        for (int k = 0; k < BKT; ++k) {
            float4 avv = *(const float4*)&As[k][ty * 4];
            float4 bvv = *(const float4*)&Bs[k][tx * 4];
            const float* av = &avv.x;
            const float* bv = &bvv.x;
#pragma unroll
            for (int i = 0; i < 4; ++i)
#pragma unroll
                for (int j = 0; j < 4; ++j)
                    acc[i][j] = fmaf(av[i], bv[j], acc[i][j]);
        }
    }

#pragma unroll
    for (int i = 0; i < 4; ++i) {
        float4 o;
        o.x = acc[i][0] + bias[n0 + tx * 4 + 0];
        o.y = acc[i][1] + bias[n0 + tx * 4 + 1];
        o.z = acc[i][2] + bias[n0 + tx * 4 + 2];
        o.w = acc[i][3] + bias[n0 + tx * 4 + 3];
        *(float4*)&C[(size_t)(m0 + ty * 4 + i) * N + n0 + tx * 4] = o;
    }
}

// ---------------------------------------------------------------------------
// Recurrence v2: 64 blocks (1 batch element), 1024 threads (16 waves).
// thread = (j = tid>>2 hidden unit, s = tid&3 quarter of the K dim).
// Each thread holds Wh[j][64s:64s+64) as 32 f32x2 in REGISTERS (64 VGPRs —
// fits, unlike R1's 256 which spilled: VGPR_Count was 140, VALUBusy 3.7%).
// Quad-partial reduce via 2x __shfl_xor (same wave). Double-buffered h and
// xproj in LDS -> ONE __syncthreads per step. v_pk_fma_f32 halves FMA issue.
// Recurrent path stays fp32; hs stored bf16 for the output GEMM only.
// ---------------------------------------------------------------------------
#define QPAD 68   // 64 + 4 floats: quarter s starts at s*68 -> banks s*4 apart

__global__ __launch_bounds__(1024, 4) void rnn_recurrence(
    const float* __restrict__ xproj, const float* __restrict__ Wh,
    const float* __restrict__ bh, __hip_bfloat16* __restrict__ hs)
{
    __shared__ __align__(16) float hbuf[2][4 * QPAD];  // padded quarters
    __shared__ __align__(16) float xpbuf[2][HH];

    const int b   = blockIdx.x;
    const int tid = threadIdx.x;
    const int j   = tid >> 2;   // hidden unit 0..255
    const int s   = tid & 3;    // K-quarter 0..3

    // Wh[j][64s .. 64s+63] into registers as 32 packed pairs
    const float* wrow = Wh + (size_t)j * HH + s * 64;
    f32x2 whq[32];
#pragma unroll
    for (int q = 0; q < 16; ++q) {
        float4 v = *(const float4*)&wrow[4 * q];
        whq[2 * q + 0] = f32x2{v.x, v.y};
        whq[2 * q + 1] = f32x2{v.z, v.w};
    }
    const float bhv = bh[j];

    const float* xp_b = xproj + (size_t)b * TT * HH;
    __hip_bfloat16* hout = hs + (size_t)b * TT * HH;

    // prologue: h0 = 0, stage xproj[0]
    if (tid < 2 * 4 * QPAD) ((float*)hbuf)[tid] = 0.0f;
    if (tid < HH) xpbuf[0][tid] = xp_b[tid];
    __syncthreads();

    int p = 0;
    for (int t = 0; t < TT; ++t) {
        // prefetch next timestep's xproj (latency hidden under the dot)
        float xnext = 0.0f;
        if (tid < HH) {
            int tn = (t + 1 < TT) ? (t + 1) : (TT - 1);
            xnext = xp_b[(size_t)tn * HH + tid];
        }

        // 64-MAC quarter-dot against broadcast LDS reads of h
        f32x2 acc0 = {0.f, 0.f}, acc1 = {0.f, 0.f};
        const float4* h4 = (const float4*)&hbuf[p][s * QPAD];
#pragma unroll
        for (int q = 0; q < 16; ++q) {
            float4 hv = h4[q];
            f32x2 hlo = {hv.x, hv.y};
            f32x2 hhi = {hv.z, hv.w};
            asm("v_pk_fma_f32 %0, %1, %2, %0" : "+v"(acc0) : "v"(whq[2 * q + 0]), "v"(hlo));
            asm("v_pk_fma_f32 %0, %1, %2, %0" : "+v"(acc1) : "v"(whq[2 * q + 1]), "v"(hhi));
        }
        float sum = (acc0[0] + acc0[1]) + (acc1[0] + acc1[1]);

        // quad reduce: partials for unit j live in lanes 4j..4j+3 of one wave
        sum += __shfl_xor(sum, 1);
        sum += __shfl_xor(sum, 2);

        float xpv = xpbuf[p][j];                  // 4-lane broadcast read
        float h = tanhf(sum + xpv + bhv);

        if (s == 0) {
            hbuf[p ^ 1][(j >> 6) * QPAD + (j & 63)] = h;
            hout[(size_t)t * HH + j] = __float2bfloat16(h);
        }
        if (tid < HH) xpbuf[p ^ 1][tid] = xnext;

        __syncthreads();   // single barrier: writes to buffers p^1 now visible
        p ^= 1;
    }
}

// ---------------------------------------------------------------------------
extern "C" void kernel_launch(void* const* d_in, const int* in_sizes, int n_in,
                              void* d_out, int out_size, void* d_ws, size_t ws_size,
                              hipStream_t stream)
{
    const float* x  = (const float*)d_in[0];   // [B,T,I]
    const float* Wi = (const float*)d_in[1];   // [H,I]
    const float* bi = (const float*)d_in[2];   // [H]
    const float* Wh = (const float*)d_in[3];   // [H,H]
    const float* bh = (const float*)d_in[4];   // [H]
    const float* Wo = (const float*)d_in[5];   // [O,H]
    const float* bo = (const float*)d_in[6];   // [O]
    float* out = (float*)d_out;                // [B,T,O] fp32

    const int M = BB * TT;                     // 131072 flattened rows

    // workspace layout: xproj fp32 [M,H] (134MB) | hs bf16 [M,H] (67MB)
    float* xproj = (float*)d_ws;
    __hip_bfloat16* hs = (__hip_bfloat16*)((char*)d_ws + (size_t)M * HH * sizeof(float));

    // Phase 1: xproj = x * Wi^T + bi
    gemm_f32_bt<<<dim3(M / BM, HH / BN), 256, 0, stream>>>(x, Wi, bi, xproj, M, HH, II);

    // Phase 2: sequential recurrence over T, parallel over batch
    rnn_recurrence<<<dim3(BB), 1024, 0, stream>>>(xproj, Wh, bh, hs);

    // Phase 3: out = hs * Wo^T + bo
    gemm_bf16a_bt<<<dim3(M / BM, OO / BN), 256, 0, stream>>>(
        (const unsigned short*)hs, Wo, bo, out, M, OO, HH);
}

// Round 3
// 2241.951 us; speedup vs baseline: 2.0643x; 1.0037x over previous
//
#include <hip/hip_runtime.h>
#include <hip/hip_bf16.h>

// Problem constants
#define BB 64
#define TT 2048
#define II 128
#define HH 256
#define OO 128

typedef float f32x2 __attribute__((ext_vector_type(2)));

// ---------------------------------------------------------------------------
// Tiled fp32 GEMM: C[M,N] = A[M,K] * B[N,K]^T + bias[N]   (unchanged)
// ---------------------------------------------------------------------------
#define BM 64
#define BN 64
#define BKT 32

__global__ __launch_bounds__(256) void gemm_f32_bt(
    const float* __restrict__ A, const float* __restrict__ B,
    const float* __restrict__ bias, float* __restrict__ C,
    int M, int N, int K)
{
    __shared__ __align__(16) float As[BKT][BM + 4];
    __shared__ __align__(16) float Bs[BKT][BN + 4];

    const int t  = threadIdx.x;
    const int m0 = blockIdx.x * BM;
    const int n0 = blockIdx.y * BN;
    const int r  = t >> 3;         // 0..31
    const int kq = (t & 7) * 4;    // 0,4,...,28
    const int tx = t & 15;
    const int ty = t >> 4;

    float acc[4][4] = {};

    for (int k0 = 0; k0 < K; k0 += BKT) {
        float4 a0 = *(const float4*)&A[(size_t)(m0 + r)      * K + k0 + kq];
        float4 a1 = *(const float4*)&A[(size_t)(m0 + r + 32) * K + k0 + kq];
        float4 b0 = *(const float4*)&B[(size_t)(n0 + r)      * K + k0 + kq];
        float4 b1 = *(const float4*)&B[(size_t)(n0 + r + 32) * K + k0 + kq];

        __syncthreads();
        As[kq + 0][r] = a0.x; As[kq + 1][r] = a0.y; As[kq + 2][r] = a0.z; As[kq + 3][r] = a0.w;
        As[kq + 0][r + 32] = a1.x; As[kq + 1][r + 32] = a1.y; As[kq + 2][r + 32] = a1.z; As[kq + 3][r + 32] = a1.w;
        Bs[kq + 0][r] = b0.x; Bs[kq + 1][r] = b0.y; Bs[kq + 2][r] = b0.z; Bs[kq + 3][r] = b0.w;
        Bs[kq + 0][r + 32] = b1.x; Bs[kq + 1][r + 32] = b1.y; Bs[kq + 2][r + 32] = b1.z; Bs[kq + 3][r + 32] = b1.w;
        __syncthreads();

#pragma unroll
        for (int k = 0; k < BKT; ++k) {
            float4 avv = *(const float4*)&As[k][ty * 4];
            float4 bvv = *(const float4*)&Bs[k][tx * 4];
            const float* av = &avv.x;
            const float* bv = &bvv.x;
#pragma unroll
            for (int i = 0; i < 4; ++i)
#pragma unroll
                for (int j = 0; j < 4; ++j)
                    acc[i][j] = fmaf(av[i], bv[j], acc[i][j]);
        }
    }

#pragma unroll
    for (int i = 0; i < 4; ++i) {
        float4 o;
        o.x = acc[i][0] + bias[n0 + tx * 4 + 0];
        o.y = acc[i][1] + bias[n0 + tx * 4 + 1];
        o.z = acc[i][2] + bias[n0 + tx * 4 + 2];
        o.w = acc[i][3] + bias[n0 + tx * 4 + 3];
        *(float4*)&C[(size_t)(m0 + ty * 4 + i) * N + n0 + tx * 4] = o;
    }
}

// Same GEMM but A is bf16 (hs), output fp32.  (unchanged)
typedef unsigned short ushortv4 __attribute__((ext_vector_type(4)));

__device__ __forceinline__ float bf16bits_to_f32(unsigned short u) {
    return __uint_as_float((unsigned)u << 16);
}

__global__ __launch_bounds__(256) void gemm_bf16a_bt(
    const unsigned short* __restrict__ A, const float* __restrict__ B,
    const float* __restrict__ bias, float* __restrict__ C,
    int M, int N, int K)
{
    __shared__ __align__(16) float As[BKT][BM + 4];
    __shared__ __align__(16) float Bs[BKT][BN + 4];

    const int t  = threadIdx.x;
    const int m0 = blockIdx.x * BM;
    const int n0 = blockIdx.y * BN;
    const int r  = t >> 3;
    const int kq = (t & 7) * 4;
    const int tx = t & 15;
    const int ty = t >> 4;

    float acc[4][4] = {};

    for (int k0 = 0; k0 < K; k0 += BKT) {
        ushortv4 a0 = *(const ushortv4*)&A[(size_t)(m0 + r)      * K + k0 + kq];
        ushortv4 a1 = *(const ushortv4*)&A[(size_t)(m0 + r + 32) * K + k0 + kq];
        float4  b0 = *(const float4*)&B[(size_t)(n0 + r)      * K + k0 + kq];
        float4  b1 = *(const float4*)&B[(size_t)(n0 + r + 32) * K + k0 + kq];

        __syncthreads();
        As[kq + 0][r] = bf16bits_to_f32(a0[0]); As[kq + 1][r] = bf16bits_to_f32(a0[1]);
        As[kq + 2][r] = bf16bits_to_f32(a0[2]); As[kq + 3][r] = bf16bits_to_f32(a0[3]);
        As[kq + 0][r + 32] = bf16bits_to_f32(a1[0]); As[kq + 1][r + 32] = bf16bits_to_f32(a1[1]);
        As[kq + 2][r + 32] = bf16bits_to_f32(a1[2]); As[kq + 3][r + 32] = bf16bits_to_f32(a1[3]);
        Bs[kq + 0][r] = b0.x; Bs[kq + 1][r] = b0.y; Bs[kq + 2][r] = b0.z; Bs[kq + 3][r] = b0.w;
        Bs[kq + 0][r + 32] = b1.x; Bs[kq + 1][r + 32] = b1.y; Bs[kq + 2][r + 32] = b1.z; Bs[kq + 3][r + 32] = b1.w;
        __syncthreads();

#pragma unroll
        for (int k = 0; k < BKT; ++k) {
            float4 avv = *(const float4*)&As[k][ty * 4];
            float4 bvv = *(const float4*)&Bs[k][tx * 4];
            const float* av = &avv.x;
            const float* bv = &bvv.x;
#pragma unroll
            for (int i = 0; i < 4; ++i)
#pragma unroll
                for (int j = 0; j < 4; ++j)
                    acc[i][j] = fmaf(av[i], bv[j], acc[i][j]);
        }
    }

#pragma unroll
    for (int i = 0; i < 4; ++i) {
        float4 o;
        o.x = acc[i][0] + bias[n0 + tx * 4 + 0];
        o.y = acc[i][1] + bias[n0 + tx * 4 + 1];
        o.z = acc[i][2] + bias[n0 + tx * 4 + 2];
        o.w = acc[i][3] + bias[n0 + tx * 4 + 3];
        *(float4*)&C[(size_t)(m0 + ty * 4 + i) * N + n0 + tx * 4] = o;
    }
}

// ---------------------------------------------------------------------------
// Recurrence v3: 64 blocks x 1024 threads; thread = (j=tid>>2, s=tid&3).
// R2 failure: VGPR_Count=48 -> whq[32] array was demoted to scratch/reload
// (rule #20: array indexing must be compile-time; plus scheduler pressure).
// Fix: 32 NAMED f32x2 weight registers (macro-expanded, no arrays, no loops)
// and the dot manually chunked 4x{4 h-reads + 8 pk_fma} with sched_barrier(0)
// between chunks so peak live h-regs = 16 -> total pressure ~100 < 128 cap.
// ---------------------------------------------------------------------------
#define QPAD 68   // 64 + 4 floats: quarter s starts at s*68

__global__ __launch_bounds__(1024, 4) void rnn_recurrence(
    const float* __restrict__ xproj, const float* __restrict__ Wh,
    const float* __restrict__ bh, __hip_bfloat16* __restrict__ hs)
{
    __shared__ __align__(16) float hbuf[2][4 * QPAD];
    __shared__ __align__(16) float xpbuf[2][HH];

    const int b   = blockIdx.x;
    const int tid = threadIdx.x;
    const int j   = tid >> 2;   // hidden unit 0..255
    const int s   = tid & 3;    // K-quarter 0..3

    const float* wrow = Wh + (size_t)j * HH + s * 64;

    // 32 NAMED weight register pairs — no array, cannot be demoted.
#define DECLW(q) f32x2 w##q##a, w##q##b;
    DECLW(0) DECLW(1) DECLW(2) DECLW(3) DECLW(4) DECLW(5) DECLW(6) DECLW(7)
    DECLW(8) DECLW(9) DECLW(10) DECLW(11) DECLW(12) DECLW(13) DECLW(14) DECLW(15)
#define LOADW(q) { float4 v = *(const float4*)&wrow[4 * (q)]; \
                   w##q##a = f32x2{v.x, v.y}; w##q##b = f32x2{v.z, v.w}; }
    LOADW(0) LOADW(1) LOADW(2) LOADW(3) LOADW(4) LOADW(5) LOADW(6) LOADW(7)
    LOADW(8) LOADW(9) LOADW(10) LOADW(11) LOADW(12) LOADW(13) LOADW(14) LOADW(15)

    const float bhv = bh[j];

    const float* xp_b = xproj + (size_t)b * TT * HH;
    __hip_bfloat16* hout = hs + (size_t)b * TT * HH;

    // prologue: h0 = 0, stage xproj[0]
    if (tid < 2 * 4 * QPAD) ((float*)hbuf)[tid] = 0.0f;
    if (tid < HH) xpbuf[0][tid] = xp_b[tid];
    __syncthreads();

    int p = 0;
    for (int t = 0; t < TT; ++t) {
        // prefetch next timestep's xproj (hidden under the dot)
        float xnext = 0.0f;
        if (tid < HH) {
            int tn = (t + 1 < TT) ? (t + 1) : (TT - 1);
            xnext = xp_b[(size_t)tn * HH + tid];
        }

        f32x2 acc0 = {0.f, 0.f}, acc1 = {0.f, 0.f};
        const float4* h4 = (const float4*)&hbuf[p][s * QPAD];

        // one chunk = 4 wave-uniform float4 LDS reads + 8 packed FMAs
#define DOT1(q, hv) { \
            f32x2 hlo = {hv.x, hv.y}, hhi = {hv.z, hv.w}; \
            asm("v_pk_fma_f32 %0, %1, %2, %0" : "+v"(acc0) : "v"(w##q##a), "v"(hlo)); \
            asm("v_pk_fma_f32 %0, %1, %2, %0" : "+v"(acc1) : "v"(w##q##b), "v"(hhi)); }
#define CHUNK(q0, q1, q2, q3) { \
            float4 h0v = h4[q0], h1v = h4[q1], h2v = h4[q2], h3v = h4[q3]; \
            DOT1(q0, h0v) DOT1(q1, h1v) DOT1(q2, h2v) DOT1(q3, h3v) }

        CHUNK(0, 1, 2, 3)
        __builtin_amdgcn_sched_barrier(0);   // cap in-flight h regs at 16
        CHUNK(4, 5, 6, 7)
        __builtin_amdgcn_sched_barrier(0);
        CHUNK(8, 9, 10, 11)
        __builtin_amdgcn_sched_barrier(0);
        CHUNK(12, 13, 14, 15)

        float sum = (acc0[0] + acc0[1]) + (acc1[0] + acc1[1]);

        // quad reduce: partials for unit j live in lanes 4j..4j+3 of one wave
        sum += __shfl_xor(sum, 1);
        sum += __shfl_xor(sum, 2);

        float xpv = xpbuf[p][j];
        float h = tanhf(sum + xpv + bhv);

        if (s == 0) {
            hbuf[p ^ 1][(j >> 6) * QPAD + (j & 63)] = h;
            hout[(size_t)t * HH + j] = __float2bfloat16(h);
        }
        if (tid < HH) xpbuf[p ^ 1][tid] = xnext;

        __syncthreads();
        p ^= 1;
    }
}

// ---------------------------------------------------------------------------
extern "C" void kernel_launch(void* const* d_in, const int* in_sizes, int n_in,
                              void* d_out, int out_size, void* d_ws, size_t ws_size,
                              hipStream_t stream)
{
    const float* x  = (const float*)d_in[0];   // [B,T,I]
    const float* Wi = (const float*)d_in[1];   // [H,I]
    const float* bi = (const float*)d_in[2];   // [H]
    const float* Wh = (const float*)d_in[3];   // [H,H]
    const float* bh = (const float*)d_in[4];   // [H]
    const float* Wo = (const float*)d_in[5];   // [O,H]
    const float* bo = (const float*)d_in[6];   // [O]
    float* out = (float*)d_out;                // [B,T,O] fp32

    const int M = BB * TT;                     // 131072 flattened rows

    // workspace layout: xproj fp32 [M,H] (134MB) | hs bf16 [M,H] (67MB)
    float* xproj = (float*)d_ws;
    __hip_bfloat16* hs = (__hip_bfloat16*)((char*)d_ws + (size_t)M * HH * sizeof(float));

    // Phase 1: xproj = x * Wi^T + bi
    gemm_f32_bt<<<dim3(M / BM, HH / BN), 256, 0, stream>>>(x, Wi, bi, xproj, M, HH, II);

    // Phase 2: sequential recurrence over T, parallel over batch
    rnn_recurrence<<<dim3(BB), 1024, 0, stream>>>(xproj, Wh, bh, hs);

    // Phase 3: out = hs * Wo^T + bo
    gemm_bf16a_bt<<<dim3(M / BM, OO / BN), 256, 0, stream>>>(
        (const unsigned short*)hs, Wo, bo, out, M, OO, HH);
}

// Round 4
// 1754.980 us; speedup vs baseline: 2.6371x; 1.2775x over previous
//
#include <hip/hip_runtime.h>
#include <hip/hip_bf16.h>

// Problem constants
#define BB 64
#define TT 2048
#define II 128
#define HH 256
#define OO 128

typedef float f32x2 __attribute__((ext_vector_type(2)));

// ---------------------------------------------------------------------------
// Tiled fp32 GEMM: C[M,N] = A[M,K] * B[N,K]^T + bias[N]   (unchanged)
// ---------------------------------------------------------------------------
#define BM 64
#define BN 64
#define BKT 32

__global__ __launch_bounds__(256) void gemm_f32_bt(
    const float* __restrict__ A, const float* __restrict__ B,
    const float* __restrict__ bias, float* __restrict__ C,
    int M, int N, int K)
{
    __shared__ __align__(16) float As[BKT][BM + 4];
    __shared__ __align__(16) float Bs[BKT][BN + 4];

    const int t  = threadIdx.x;
    const int m0 = blockIdx.x * BM;
    const int n0 = blockIdx.y * BN;
    const int r  = t >> 3;         // 0..31
    const int kq = (t & 7) * 4;    // 0,4,...,28
    const int tx = t & 15;
    const int ty = t >> 4;

    float acc[4][4] = {};

    for (int k0 = 0; k0 < K; k0 += BKT) {
        float4 a0 = *(const float4*)&A[(size_t)(m0 + r)      * K + k0 + kq];
        float4 a1 = *(const float4*)&A[(size_t)(m0 + r + 32) * K + k0 + kq];
        float4 b0 = *(const float4*)&B[(size_t)(n0 + r)      * K + k0 + kq];
        float4 b1 = *(const float4*)&B[(size_t)(n0 + r + 32) * K + k0 + kq];

        __syncthreads();
        As[kq + 0][r] = a0.x; As[kq + 1][r] = a0.y; As[kq + 2][r] = a0.z; As[kq + 3][r] = a0.w;
        As[kq + 0][r + 32] = a1.x; As[kq + 1][r + 32] = a1.y; As[kq + 2][r + 32] = a1.z; As[kq + 3][r + 32] = a1.w;
        Bs[kq + 0][r] = b0.x; Bs[kq + 1][r] = b0.y; Bs[kq + 2][r] = b0.z; Bs[kq + 3][r] = b0.w;
        Bs[kq + 0][r + 32] = b1.x; Bs[kq + 1][r + 32] = b1.y; Bs[kq + 2][r + 32] = b1.z; Bs[kq + 3][r + 32] = b1.w;
        __syncthreads();

#pragma unroll
        for (int k = 0; k < BKT; ++k) {
            float4 avv = *(const float4*)&As[k][ty * 4];
            float4 bvv = *(const float4*)&Bs[k][tx * 4];
            const float* av = &avv.x;
            const float* bv = &bvv.x;
#pragma unroll
            for (int i = 0; i < 4; ++i)
#pragma unroll
                for (int j = 0; j < 4; ++j)
                    acc[i][j] = fmaf(av[i], bv[j], acc[i][j]);
        }
    }

#pragma unroll
    for (int i = 0; i < 4; ++i) {
        float4 o;
        o.x = acc[i][0] + bias[n0 + tx * 4 + 0];
        o.y = acc[i][1] + bias[n0 + tx * 4 + 1];
        o.z = acc[i][2] + bias[n0 + tx * 4 + 2];
        o.w = acc[i][3] + bias[n0 + tx * 4 + 3];
        *(float4*)&C[(size_t)(m0 + ty * 4 + i) * N + n0 + tx * 4] = o;
    }
}

// Same GEMM but A is bf16 (hs), output fp32.  (unchanged)
typedef unsigned short ushortv4 __attribute__((ext_vector_type(4)));

__device__ __forceinline__ float bf16bits_to_f32(unsigned short u) {
    return __uint_as_float((unsigned)u << 16);
}

__global__ __launch_bounds__(256) void gemm_bf16a_bt(
    const unsigned short* __restrict__ A, const float* __restrict__ B,
    const float* __restrict__ bias, float* __restrict__ C,
    int M, int N, int K)
{
    __shared__ __align__(16) float As[BKT][BM + 4];
    __shared__ __align__(16) float Bs[BKT][BN + 4];

    const int t  = threadIdx.x;
    const int m0 = blockIdx.x * BM;
    const int n0 = blockIdx.y * BN;
    const int r  = t >> 3;
    const int kq = (t & 7) * 4;
    const int tx = t & 15;
    const int ty = t >> 4;

    float acc[4][4] = {};

    for (int k0 = 0; k0 < K; k0 += BKT) {
        ushortv4 a0 = *(const ushortv4*)&A[(size_t)(m0 + r)      * K + k0 + kq];
        ushortv4 a1 = *(const ushortv4*)&A[(size_t)(m0 + r + 32) * K + k0 + kq];
        float4  b0 = *(const float4*)&B[(size_t)(n0 + r)      * K + k0 + kq];
        float4  b1 = *(const float4*)&B[(size_t)(n0 + r + 32) * K + k0 + kq];

        __syncthreads();
        As[kq + 0][r] = bf16bits_to_f32(a0[0]); As[kq + 1][r] = bf16bits_to_f32(a0[1]);
        As[kq + 2][r] = bf16bits_to_f32(a0[2]); As[kq + 3][r] = bf16bits_to_f32(a0[3]);
        As[kq + 0][r + 32] = bf16bits_to_f32(a1[0]); As[kq + 1][r + 32] = bf16bits_to_f32(a1[1]);
        As[kq + 2][r + 32] = bf16bits_to_f32(a1[2]); As[kq + 3][r + 32] = bf16bits_to_f32(a1[3]);
        Bs[kq + 0][r] = b0.x; Bs[kq + 1][r] = b0.y; Bs[kq + 2][r] = b0.z; Bs[kq + 3][r] = b0.w;
        Bs[kq + 0][r + 32] = b1.x; Bs[kq + 1][r + 32] = b1.y; Bs[kq + 2][r + 32] = b1.z; Bs[kq + 3][r + 32] = b1.w;
        __syncthreads();

#pragma unroll
        for (int k = 0; k < BKT; ++k) {
            float4 avv = *(const float4*)&As[k][ty * 4];
            float4 bvv = *(const float4*)&Bs[k][tx * 4];
            const float* av = &avv.x;
            const float* bv = &bvv.x;
#pragma unroll
            for (int i = 0; i < 4; ++i)
#pragma unroll
                for (int j = 0; j < 4; ++j)
                    acc[i][j] = fmaf(av[i], bv[j], acc[i][j]);
        }
    }

#pragma unroll
    for (int i = 0; i < 4; ++i) {
        float4 o;
        o.x = acc[i][0] + bias[n0 + tx * 4 + 0];
        o.y = acc[i][1] + bias[n0 + tx * 4 + 1];
        o.z = acc[i][2] + bias[n0 + tx * 4 + 2];
        o.w = acc[i][3] + bias[n0 + tx * 4 + 3];
        *(float4*)&C[(size_t)(m0 + ty * 4 + i) * N + n0 + tx * 4] = o;
    }
}

// ---------------------------------------------------------------------------
// Recurrence v4. R3 failure: VGPR=52 — backend sank the (legal-to-reissue)
// weight loads into the loop chasing higher occupancy (launch_bounds 2nd arg
// is only a MINIMUM). Fixes:
//  (a) amdgpu_waves_per_eu(4,4): budget pinned at 128 VGPR, no shrink incentive
//  (b) every pk_fma declares its weight "+v" (read-write): the weight becomes
//      a loop-carried asm def -> reload is ILLEGAL, must stay in VGPRs
//  (c) thread = (unit pair jb/jb+128, 8-way K-segment of 32): 8 ds_read_b128
//      per step (was 16); pad 36 -> all-32-bank conflict-free broadcast
//  (d) 8-lane reduce via DPP quad_perm xor1/xor2 + ROW_HALF_MIRROR (xor7
//      pairs the quads) -> zero LDS ops in the reduction
//  (e) tanh = 1 - 2*rcp(exp(2x)+1) (exact identity, ~5 VALU ops)
// ---------------------------------------------------------------------------
#define SPAD 36   // 32 + 4 pad words per K-segment

__device__ __forceinline__ float dpp_add8(float x) {
    // reduce over 8 consecutive lanes: xor1, xor2 (quad_perm), xor7 (half mirror)
    x += __uint_as_float(__builtin_amdgcn_mov_dpp(__float_as_uint(x), 0xB1, 0xF, 0xF, true));
    x += __uint_as_float(__builtin_amdgcn_mov_dpp(__float_as_uint(x), 0x4E, 0xF, 0xF, true));
    x += __uint_as_float(__builtin_amdgcn_mov_dpp(__float_as_uint(x), 0x141, 0xF, 0xF, true));
    return x;
}

__device__ __forceinline__ float tanh_fast(float x) {
    float e = __expf(2.0f * x);                       // v_mul + v_exp
    return 1.0f - 2.0f * __builtin_amdgcn_rcpf(e + 1.0f);
}

__global__ __launch_bounds__(1024) __attribute__((amdgpu_waves_per_eu(4, 4)))
void rnn_recurrence(
    const float* __restrict__ xproj, const float* __restrict__ Wh,
    const float* __restrict__ bh, __hip_bfloat16* __restrict__ hs)
{
    __shared__ __align__(16) float hbuf[2][8 * SPAD];
    __shared__ __align__(16) float xpbuf[2][HH];

    const int b   = blockIdx.x;
    const int tid = threadIdx.x;
    const int jb  = tid >> 3;        // 0..127: this thread owns units jb and jb+128
    const int s   = tid & 7;         // K-segment (32 wide)

    const float* w0p = Wh + (size_t)jb * HH + s * 32;
    const float* w1p = Wh + (size_t)(jb + 128) * HH + s * 32;

    // 32 NAMED f32x2 weight pairs (16 per unit)
    f32x2 wa0, wa1, wa2, wa3, wa4, wa5, wa6, wa7,
          wa8, wa9, wa10, wa11, wa12, wa13, wa14, wa15;
    f32x2 wb0, wb1, wb2, wb3, wb4, wb5, wb6, wb7,
          wb8, wb9, wb10, wb11, wb12, wb13, wb14, wb15;
#define LOADP(ptr, q, r0, r1) { float4 v = *(const float4*)&(ptr)[4 * (q)]; \
                                r0 = f32x2{v.x, v.y}; r1 = f32x2{v.z, v.w}; }
    LOADP(w0p, 0, wa0, wa1)   LOADP(w0p, 1, wa2, wa3)
    LOADP(w0p, 2, wa4, wa5)   LOADP(w0p, 3, wa6, wa7)
    LOADP(w0p, 4, wa8, wa9)   LOADP(w0p, 5, wa10, wa11)
    LOADP(w0p, 6, wa12, wa13) LOADP(w0p, 7, wa14, wa15)
    LOADP(w1p, 0, wb0, wb1)   LOADP(w1p, 1, wb2, wb3)
    LOADP(w1p, 2, wb4, wb5)   LOADP(w1p, 3, wb6, wb7)
    LOADP(w1p, 4, wb8, wb9)   LOADP(w1p, 5, wb10, wb11)
    LOADP(w1p, 6, wb12, wb13) LOADP(w1p, 7, wb14, wb15)

    const float bh0 = bh[jb];
    const float bh1 = bh[jb + 128];

    const float* xp_b = xproj + (size_t)b * TT * HH;
    __hip_bfloat16* hout = hs + (size_t)b * TT * HH;

    // prologue: h0 = 0 (both buffers), stage xproj[0]
    if (tid < 2 * 8 * SPAD) ((float*)hbuf)[tid] = 0.0f;
    if (tid < HH) xpbuf[0][tid] = xp_b[tid];
    __syncthreads();

    int p = 0;
    for (int t = 0; t < TT; ++t) {
        // prefetch next timestep's xproj (hidden under the dot)
        float xn = 0.0f;
        if (tid < HH) {
            int tn = (t + 1 < TT) ? (t + 1) : (TT - 1);
            xn = xp_b[(size_t)tn * HH + tid];
        }

        f32x2 accA0 = {0.f, 0.f}, accA1 = {0.f, 0.f};
        f32x2 accB0 = {0.f, 0.f}, accB1 = {0.f, 0.f};
        const float4* h4 = (const float4*)&hbuf[p][s * SPAD];

        // weight operands are "+v": fake read-write makes them loop-carried asm
        // defs -> compiler CANNOT re-load them from memory inside the loop.
#define DOTQ(q, a0r, a1r, b0r, b1r) { \
        float4 hv = h4[q]; \
        f32x2 hl = {hv.x, hv.y}, hh2 = {hv.z, hv.w}; \
        asm("v_pk_fma_f32 %0, %1, %2, %0" : "+v"(accA0), "+v"(a0r) : "v"(hl)); \
        asm("v_pk_fma_f32 %0, %1, %2, %0" : "+v"(accA1), "+v"(a1r) : "v"(hh2)); \
        asm("v_pk_fma_f32 %0, %1, %2, %0" : "+v"(accB0), "+v"(b0r) : "v"(hl)); \
        asm("v_pk_fma_f32 %0, %1, %2, %0" : "+v"(accB1), "+v"(b1r) : "v"(hh2)); }

        DOTQ(0, wa0,  wa1,  wb0,  wb1)
        DOTQ(1, wa2,  wa3,  wb2,  wb3)
        DOTQ(2, wa4,  wa5,  wb4,  wb5)
        DOTQ(3, wa6,  wa7,  wb6,  wb7)
        DOTQ(4, wa8,  wa9,  wb8,  wb9)
        DOTQ(5, wa10, wa11, wb10, wb11)
        DOTQ(6, wa12, wa13, wb12, wb13)
        DOTQ(7, wa14, wa15, wb14, wb15)

        float sumA = (accA0[0] + accA0[1]) + (accA1[0] + accA1[1]);
        float sumB = (accB0[0] + accB0[1]) + (accB1[0] + accB1[1]);
        sumA = dpp_add8(sumA);
        sumB = dpp_add8(sumB);

        float h0v = tanh_fast(sumA + xpbuf[p][jb] + bh0);
        float h1v = tanh_fast(sumB + xpbuf[p][jb + 128] + bh1);

        if (s == 0) {
            const int seg = jb >> 5, off = jb & 31;
            hbuf[p ^ 1][seg * SPAD + off] = h0v;
            hbuf[p ^ 1][(4 + seg) * SPAD + off] = h1v;
            hout[(size_t)t * HH + jb] = __float2bfloat16(h0v);
            hout[(size_t)t * HH + jb + 128] = __float2bfloat16(h1v);
        }
        if (tid < HH) xpbuf[p ^ 1][tid] = xn;

        __syncthreads();
        p ^= 1;
    }
}

// ---------------------------------------------------------------------------
extern "C" void kernel_launch(void* const* d_in, const int* in_sizes, int n_in,
                              void* d_out, int out_size, void* d_ws, size_t ws_size,
                              hipStream_t stream)
{
    const float* x  = (const float*)d_in[0];   // [B,T,I]
    const float* Wi = (const float*)d_in[1];   // [H,I]
    const float* bi = (const float*)d_in[2];   // [H]
    const float* Wh = (const float*)d_in[3];   // [H,H]
    const float* bh = (const float*)d_in[4];   // [H]
    const float* Wo = (const float*)d_in[5];   // [O,H]
    const float* bo = (const float*)d_in[6];   // [O]
    float* out = (float*)d_out;                // [B,T,O] fp32

    const int M = BB * TT;                     // 131072 flattened rows

    // workspace layout: xproj fp32 [M,H] (134MB) | hs bf16 [M,H] (67MB)
    float* xproj = (float*)d_ws;
    __hip_bfloat16* hs = (__hip_bfloat16*)((char*)d_ws + (size_t)M * HH * sizeof(float));

    // Phase 1: xproj = x * Wi^T + bi
    gemm_f32_bt<<<dim3(M / BM, HH / BN), 256, 0, stream>>>(x, Wi, bi, xproj, M, HH, II);

    // Phase 2: sequential recurrence over T, parallel over batch
    rnn_recurrence<<<dim3(BB), 1024, 0, stream>>>(xproj, Wh, bh, hs);

    // Phase 3: out = hs * Wo^T + bo
    gemm_bf16a_bt<<<dim3(M / BM, OO / BN), 256, 0, stream>>>(
        (const unsigned short*)hs, Wo, bo, out, M, OO, HH);
}